// Round 15
// baseline (185.015 us; speedup 1.0000x reference)
//
#include <hip/hip_runtime.h>

typedef short bf16x8 __attribute__((ext_vector_type(8)));
typedef float f32x4 __attribute__((ext_vector_type(4)));
typedef unsigned short ushort8 __attribute__((ext_vector_type(8)));

#define S_SZ 2048
#define D_SZ 512
#define NB 8

__device__ __forceinline__ unsigned short f2bf(float f) {
    unsigned int u = __float_as_uint(f);
    unsigned int r = (u + 0x7FFFu + ((u >> 16) & 1u)) >> 16;
    return (unsigned short)r;
}
__device__ __forceinline__ float bf2f(unsigned short u) {
    return __uint_as_float((unsigned int)u << 16);
}

// ---------------------------------------------------------------------------
// scores8: e = exp((qp @ kp^T) * inv_scale) -> bf16 sc, + atomic rowsum.
// 256x256 tile, BK=64, 512 thr = 8 waves (2M x 4N). T2 XOR-swizzled LDS.
// Stage order B0,B1,A0,A1 (oldest = needed-first); boundary = ONE barrier
// with wave-conditional counted vmcnt (wm=0 waves only need A-half0 ->
// vmcnt(2); wm=1 -> vmcnt(0)). B covered at vmcnt(2) ⊆ vmcnt(4).
// ---------------------------------------------------------------------------
__global__ __launch_bounds__(512, 2) void scores8(
    const unsigned short* __restrict__ qp, const unsigned short* __restrict__ kp,
    unsigned short* __restrict__ sc, float* __restrict__ rowsum, float inv_scale)
{
    __shared__ unsigned short Abuf[2 * 256 * 64];
    __shared__ unsigned short Bbuf[2 * 256 * 64];
    constexpr int TB = 256 * 64;

    const int tid  = threadIdx.x;
    const int lane = tid & 63;
    const int w    = tid >> 6;
    const int wm   = w >> 2;
    const int wn   = w & 3;

    const int lin = blockIdx.x;
    const int b   = lin & 7;
    const int tt  = lin >> 3;
    const int m0  = (tt & 7) * 256;
    const int n0  = (tt >> 3) * 256;

    const unsigned short* Ag = qp + (size_t)b * (S_SZ * D_SZ);
    const unsigned short* Bg = kp + (size_t)b * (S_SZ * D_SZ);

    auto stage_half = [&](int opnd, int kt, int h) {
        const int k0 = kt * 64;
        const unsigned short* src = opnd ? Bg : Ag;
        unsigned short* dstb = opnd ? Bbuf : Abuf;
        const int base0 = opnd ? n0 : m0;
        const int swzc = ((lane & 7) ^ ((lane >> 3) & 7)) * 8;
#pragma unroll
        for (int j = 0; j < 2; ++j) {
            const int chunk = w * 2 + j;
            const unsigned short* g = src +
                (size_t)(base0 + h * 128 + chunk * 8 + (lane >> 3)) * 512 +
                k0 + swzc;
            __builtin_amdgcn_global_load_lds(
                (const __attribute__((address_space(1))) unsigned int*)g,
                (__attribute__((address_space(3))) unsigned int*)
                    &dstb[(kt & 1) * TB + h * (128 * 64) + chunk * 512],
                16, 0, 0);
        }
    };

    f32x4 acc[8][4];
#pragma unroll
    for (int i = 0; i < 8; ++i)
#pragma unroll
        for (int j = 0; j < 4; ++j)
#pragma unroll
            for (int r = 0; r < 4; ++r) acc[i][j][r] = 0.f;

    stage_half(1, 0, 0); stage_half(1, 0, 1);
    stage_half(0, 0, 0); stage_half(0, 0, 1);
    asm volatile("s_waitcnt vmcnt(0)" ::: "memory");
    __builtin_amdgcn_s_barrier();
    __builtin_amdgcn_sched_barrier(0);

    int cur = 0;
    for (int kt = 0; kt < 8; ++kt) {
        bf16x8 bf[4][2];
#pragma unroll
        for (int j = 0; j < 4; ++j)
#pragma unroll
            for (int s = 0; s < 2; ++s) {
                const int row = wn * 64 + j * 16 + (lane & 15);
                const int g   = (s * 4 + (lane >> 4)) ^ (lane & 7);
                bf[j][s] = *(const bf16x8*)&Bbuf[cur * TB + row * 64 + g * 8];
            }

#pragma unroll
        for (int q = 0; q < 4; ++q) {
            bf16x8 af[2][2];
#pragma unroll
            for (int i = 0; i < 2; ++i)
#pragma unroll
                for (int s = 0; s < 2; ++s) {
                    const int row = wm * 128 + (2 * q + i) * 16 + (lane & 15);
                    const int g   = (s * 4 + (lane >> 4)) ^ (lane & 7);
                    af[i][s] = *(const bf16x8*)&Abuf[cur * TB + row * 64 + g * 8];
                }
            // oldest-first prefetch: B halves, then A halves
            if (kt + 1 < 8) {
                if      (q == 0) stage_half(1, kt + 1, 0);
                else if (q == 1) stage_half(1, kt + 1, 1);
                else if (q == 2) stage_half(0, kt + 1, 0);
                else             stage_half(0, kt + 1, 1);
            }
            __builtin_amdgcn_s_setprio(1);
#pragma unroll
            for (int i = 0; i < 2; ++i)
#pragma unroll
                for (int j = 0; j < 4; ++j)
#pragma unroll
                    for (int s = 0; s < 2; ++s)
                        acc[2 * q + i][j] = __builtin_amdgcn_mfma_f32_16x16x32_bf16(
                            af[i][s], bf[j][s], acc[2 * q + i][j], 0, 0, 0);
            __builtin_amdgcn_s_setprio(0);
        }

        // single boundary barrier + conditional partial drain
        if (wm == 0) asm volatile("s_waitcnt vmcnt(2)" ::: "memory");
        else         asm volatile("s_waitcnt vmcnt(0)" ::: "memory");
        __builtin_amdgcn_s_barrier();
        __builtin_amdgcn_sched_barrier(0);
        cur ^= 1;
    }

    const int rowb = m0 + wm * 128 + (lane >> 4) * 4;
    const int colb = n0 + wn * 64 + (lane & 15);
#pragma unroll
    for (int i = 0; i < 8; ++i) {
#pragma unroll
        for (int r = 0; r < 4; ++r) {
            const int row = rowb + i * 16 + r;
            float p = 0.f;
#pragma unroll
            for (int j = 0; j < 4; ++j) {
                const int col = colb + j * 16;
                float e = __expf(acc[i][j][r] * inv_scale);
                unsigned short eb = f2bf(e);
                sc[(size_t)b * ((long long)S_SZ * S_SZ) + (size_t)row * S_SZ + col] = eb;
                p += bf2f(eb);
            }
#pragma unroll
            for (int off = 8; off >= 1; off >>= 1) p += __shfl_xor(p, off);
            if ((lane & 15) == 0)
                atomicAdd(&rowsum[b * 2048 + row], p);
        }
    }
}

// ---------------------------------------------------------------------------
// pv8: out1 = (e @ v)/rowsum + v (bf16) AND attn fp32 = e/rowsum (nt stores).
// 256x128 tile, BK=64, 512 thr = 8 waves. T2 swizzle. Stage order B,A0,A1;
// boundary = ONE barrier; non-owned tiles: conditional vmcnt(2)/(0);
// owned tiles: vmcnt(8) (8 attn stores stay in flight).
// ---------------------------------------------------------------------------
__global__ __launch_bounds__(512, 1) void pv8(
    const unsigned short* __restrict__ sc, const unsigned short* __restrict__ vT,
    const float* __restrict__ v, unsigned short* __restrict__ out1,
    const float* __restrict__ rowsum, float* __restrict__ attnW)
{
    __shared__ unsigned short Abuf[2 * 256 * 64];
    __shared__ unsigned short Bbuf[2 * 128 * 64];
    constexpr int TA = 256 * 64;
    constexpr int TBb = 128 * 64;

    const int tid  = threadIdx.x;
    const int lane = tid & 63;
    const int w    = tid >> 6;
    const int wm   = w >> 2;
    const int wn   = w & 3;

    const int lin = blockIdx.x;
    const int b   = lin & 7;
    const int t   = lin >> 3;
    const int m0  = (t & 7) * 256;
    const int nq  = t >> 3;
    const int n0  = nq * 128;

    const unsigned short* Ag = sc + (size_t)b * ((long long)S_SZ * S_SZ);
    const unsigned short* Bg = vT + (size_t)b * (D_SZ * S_SZ);
    const int swzg = (lane & 7) ^ ((lane >> 3) & 7);

    auto stageA = [&](int kt, int h) {
#pragma unroll
        for (int j = 0; j < 2; ++j) {
            const int chunk = w * 2 + j;
            const unsigned short* g = Ag +
                (size_t)(m0 + h * 128 + chunk * 8 + (lane >> 3)) * S_SZ +
                kt * 64 + swzg * 8;
            __builtin_amdgcn_global_load_lds(
                (const __attribute__((address_space(1))) unsigned int*)g,
                (__attribute__((address_space(3))) unsigned int*)
                    &Abuf[(kt & 1) * TA + h * (128 * 64) + chunk * 512],
                16, 0, 0);
        }
    };
    auto stageB = [&](int kt) {
#pragma unroll
        for (int j = 0; j < 2; ++j) {
            const int chunk = w * 2 + j;
            const unsigned short* g = Bg +
                (size_t)(n0 + chunk * 8 + (lane >> 3)) * S_SZ +
                kt * 64 + swzg * 8;
            __builtin_amdgcn_global_load_lds(
                (const __attribute__((address_space(1))) unsigned int*)g,
                (__attribute__((address_space(3))) unsigned int*)
                    &Bbuf[(kt & 1) * TBb + chunk * 512],
                16, 0, 0);
        }
    };

    float sinv[2][2];
#pragma unroll
    for (int h = 0; h < 2; ++h)
#pragma unroll
        for (int j = 0; j < 2; ++j)
            sinv[h][j] = 1.f / rowsum[b * 2048 + m0 + h * 128 + (w * 2 + j) * 8 + (lane >> 3)];

    auto store_attn = [&](int kt, int cu) {
#pragma unroll
        for (int h = 0; h < 2; ++h)
#pragma unroll
            for (int j = 0; j < 2; ++j) {
                const int chunk = w * 2 + j;
                ushort8 ev = *(const ushort8*)&Abuf[cu * TA + h * (128 * 64) +
                                                    chunk * 512 + lane * 8];
                const float is = sinv[h][j];
                f32x4 o0, o1;
                o0[0] = bf2f(ev[0]) * is; o0[1] = bf2f(ev[1]) * is;
                o0[2] = bf2f(ev[2]) * is; o0[3] = bf2f(ev[3]) * is;
                o1[0] = bf2f(ev[4]) * is; o1[1] = bf2f(ev[5]) * is;
                o1[2] = bf2f(ev[6]) * is; o1[3] = bf2f(ev[7]) * is;
                float* dst = attnW + (size_t)b * ((long long)S_SZ * S_SZ) +
                             (size_t)(m0 + h * 128 + chunk * 8 + (lane >> 3)) * S_SZ +
                             kt * 64 + swzg * 8;
                __builtin_nontemporal_store(o0, (f32x4*)dst);
                __builtin_nontemporal_store(o1, (f32x4*)(dst + 4));
            }
    };

    f32x4 acc[8][2];
#pragma unroll
    for (int i = 0; i < 8; ++i)
#pragma unroll
        for (int j = 0; j < 2; ++j)
#pragma unroll
            for (int r = 0; r < 4; ++r) acc[i][j][r] = 0.f;

    stageB(0); stageA(0, 0); stageA(0, 1);
    asm volatile("s_waitcnt vmcnt(0)" ::: "memory");
    __builtin_amdgcn_s_barrier();
    __builtin_amdgcn_sched_barrier(0);

    int cur = 0;
    for (int kt = 0; kt < 32; ++kt) {
        const bool owned = (kt >> 3) == nq;
        bf16x8 bfr[2][2];
#pragma unroll
        for (int j = 0; j < 2; ++j)
#pragma unroll
            for (int s = 0; s < 2; ++s) {
                const int row = wn * 32 + j * 16 + (lane & 15);
                const int g   = (s * 4 + (lane >> 4)) ^ (lane & 7);
                bfr[j][s] = *(const bf16x8*)&Bbuf[cur * TBb + row * 64 + g * 8];
            }

#pragma unroll
        for (int q = 0; q < 4; ++q) {
            bf16x8 af[2][2];
#pragma unroll
            for (int i = 0; i < 2; ++i)
#pragma unroll
                for (int s = 0; s < 2; ++s) {
                    const int row = wm * 128 + (2 * q + i) * 16 + (lane & 15);
                    const int g   = (s * 4 + (lane >> 4)) ^ (lane & 7);
                    af[i][s] = *(const bf16x8*)&Abuf[cur * TA + row * 64 + g * 8];
                }
            // oldest-first: B, then A halves; attn writeback last (newest)
            if (kt + 1 < 32) {
                if      (q == 0) stageB(kt + 1);
                else if (q == 1) stageA(kt + 1, 0);
                else if (q == 2) stageA(kt + 1, 1);
            }
            if (q == 3 && owned) store_attn(kt, cur);
            __builtin_amdgcn_s_setprio(1);
#pragma unroll
            for (int i = 0; i < 2; ++i)
#pragma unroll
                for (int j = 0; j < 2; ++j)
#pragma unroll
                    for (int s = 0; s < 2; ++s)
                        acc[2 * q + i][j] = __builtin_amdgcn_mfma_f32_16x16x32_bf16(
                            af[i][s], bfr[j][s], acc[2 * q + i][j], 0, 0, 0);
            __builtin_amdgcn_s_setprio(0);
        }

        if (kt + 1 < 32) {
            if (owned)        asm volatile("s_waitcnt vmcnt(8)" ::: "memory");
            else if (wm == 0) asm volatile("s_waitcnt vmcnt(2)" ::: "memory");
            else              asm volatile("s_waitcnt vmcnt(0)" ::: "memory");
        }
        __builtin_amdgcn_s_barrier();
        __builtin_amdgcn_sched_barrier(0);
        cur ^= 1;
    }

    const int rowb = m0 + wm * 128 + (lane >> 4) * 4;
    const int colb = n0 + wn * 32 + (lane & 15);
#pragma unroll
    for (int i = 0; i < 8; ++i) {
#pragma unroll
        for (int r = 0; r < 4; ++r) {
            const int row = rowb + i * 16 + r;
            const float inv = 1.f / rowsum[b * 2048 + row];
#pragma unroll
            for (int j = 0; j < 2; ++j) {
                const int col = colb + j * 16;
                float vv = acc[i][j][r] * inv +
                           v[(size_t)b * (S_SZ * D_SZ) + (size_t)row * D_SZ + col];
                out1[(size_t)b * (S_SZ * D_SZ) + (size_t)row * D_SZ + col] = f2bf(vv);
            }
        }
    }
}

// ---------------------------------------------------------------------------
// proj256: qp = q @ w_qs^T, kp = k @ w_ks^T on the scores8 engine.
// A (fp32) reg-staged: issueA q0 (HBM-cold, 3 quadrants of latency cover),
// B halves q1/q2 (async), writeA q3. Boundary: ONE barrier with
// vmcnt(wn<2?2:0) + lgkmcnt(0) (A arrives via ds_write; B0 oldest).
// ---------------------------------------------------------------------------
__global__ __launch_bounds__(512, 1) void proj256(
    const float* __restrict__ q, const float* __restrict__ k,
    const unsigned short* __restrict__ wq, const unsigned short* __restrict__ wk,
    unsigned short* __restrict__ qp, unsigned short* __restrict__ kp)
{
    __shared__ unsigned short Abuf[2 * 256 * 64];
    __shared__ unsigned short Bbuf[2 * 256 * 64];
    constexpr int TB = 256 * 64;

    const int tid  = threadIdx.x;
    const int lane = tid & 63;
    const int w    = tid >> 6;
    const int wm   = w >> 2;
    const int wn   = w & 3;
    const int m0   = blockIdx.x * 256;
    const int n0   = blockIdx.y * 256;

    const float* Ap = blockIdx.z ? k : q;
    const unsigned short* Bp = blockIdx.z ? wk : wq;
    unsigned short* Cp = blockIdx.z ? kp : qp;

    auto stageB = [&](int kt, int h) {
        const int swzc = ((lane & 7) ^ ((lane >> 3) & 7)) * 8;
#pragma unroll
        for (int j = 0; j < 2; ++j) {
            const int chunk = w * 2 + j;
            const unsigned short* g = Bp +
                (size_t)(n0 + h * 128 + chunk * 8 + (lane >> 3)) * 512 +
                kt * 64 + swzc;
            __builtin_amdgcn_global_load_lds(
                (const __attribute__((address_space(1))) unsigned int*)g,
                (__attribute__((address_space(3))) unsigned int*)
                    &Bbuf[(kt & 1) * TB + h * (128 * 64) + chunk * 512],
                16, 0, 0);
        }
    };

    f32x4 ald[8];
    const int ar  = tid >> 1;
    const int ag0 = (tid & 1) * 4;
    auto issueA = [&](int kt) {
        const float* gp = Ap + (size_t)(m0 + ar) * 512 + kt * 64 + ag0 * 8;
#pragma unroll
        for (int u = 0; u < 8; ++u)
            ald[u] = *(const f32x4*)(gp + u * 4);
    };
    auto writeA = [&](int kt) {
#pragma unroll
        for (int gg = 0; gg < 4; ++gg) {
            ushort8 p;
#pragma unroll
            for (int u = 0; u < 4; ++u) {
                p[u]     = f2bf(ald[gg * 2][u]);
                p[4 + u] = f2bf(ald[gg * 2 + 1][u]);
            }
            const int gl = ag0 + gg;
            *(ushort8*)&Abuf[(kt & 1) * TB + ar * 64 + (gl ^ (ar & 7)) * 8] = p;
        }
    };

    f32x4 acc[8][4];
#pragma unroll
    for (int i = 0; i < 8; ++i)
#pragma unroll
        for (int j = 0; j < 4; ++j)
#pragma unroll
            for (int r = 0; r < 4; ++r) acc[i][j][r] = 0.f;

    issueA(0);
    stageB(0, 0); stageB(0, 1);
    writeA(0);
    asm volatile("s_waitcnt vmcnt(0) lgkmcnt(0)" ::: "memory");
    __builtin_amdgcn_s_barrier();
    __builtin_amdgcn_sched_barrier(0);

    int cur = 0;
    for (int kt = 0; kt < 8; ++kt) {
        bf16x8 bf[4][2];
#pragma unroll
        for (int j = 0; j < 4; ++j)
#pragma unroll
            for (int s = 0; s < 2; ++s) {
                const int row = wn * 64 + j * 16 + (lane & 15);
                const int g   = (s * 4 + (lane >> 4)) ^ (lane & 7);
                bf[j][s] = *(const bf16x8*)&Bbuf[cur * TB + row * 64 + g * 8];
            }

#pragma unroll
        for (int qd = 0; qd < 4; ++qd) {
            bf16x8 af[2][2];
#pragma unroll
            for (int i = 0; i < 2; ++i)
#pragma unroll
                for (int s = 0; s < 2; ++s) {
                    const int row = wm * 128 + (2 * qd + i) * 16 + (lane & 15);
                    const int g   = (s * 4 + (lane >> 4)) ^ (lane & 7);
                    af[i][s] = *(const bf16x8*)&Abuf[cur * TB + row * 64 + g * 8];
                }
            if (kt + 1 < 8) {
                if      (qd == 0) issueA(kt + 1);
                else if (qd == 1) stageB(kt + 1, 0);
                else if (qd == 2) stageB(kt + 1, 1);
                else              writeA(kt + 1);
            }
            __builtin_amdgcn_s_setprio(1);
#pragma unroll
            for (int i = 0; i < 2; ++i)
#pragma unroll
                for (int j = 0; j < 4; ++j)
#pragma unroll
                    for (int s = 0; s < 2; ++s)
                        acc[2 * qd + i][j] = __builtin_amdgcn_mfma_f32_16x16x32_bf16(
                            af[i][s], bf[j][s], acc[2 * qd + i][j], 0, 0, 0);
            __builtin_amdgcn_s_setprio(0);
        }

        // boundary: B0 is oldest pair after writeA's implicit A-load drain
        if (wn < 2) asm volatile("s_waitcnt vmcnt(2) lgkmcnt(0)" ::: "memory");
        else        asm volatile("s_waitcnt vmcnt(0) lgkmcnt(0)" ::: "memory");
        __builtin_amdgcn_s_barrier();
        __builtin_amdgcn_sched_barrier(0);
        cur ^= 1;
    }

    const int rowb = m0 + wm * 128 + (lane >> 4) * 4;
    const int colb = n0 + wn * 64 + (lane & 15);
#pragma unroll
    for (int i = 0; i < 8; ++i)
#pragma unroll
        for (int j = 0; j < 4; ++j) {
            const int col = colb + j * 16;
#pragma unroll
            for (int r = 0; r < 4; ++r) {
                const int row = rowb + i * 16 + r;
                Cp[(size_t)row * 512 + col] = f2bf(acc[i][j][r]);
            }
        }
}

// ---------------------------------------------------------------------------
// Fused fc GEMM + LayerNorm; out stores non-temporal (never re-read).
// ---------------------------------------------------------------------------
__global__ __launch_bounds__(512) void fc_ln(
    const unsigned short* __restrict__ A,
    const unsigned short* __restrict__ Bw,
    float* __restrict__ out,
    const float* __restrict__ ln_w, const float* __restrict__ ln_b)
{
    constexpr int BUFA = 64 * 32;
    constexpr int BUFB = 512 * 32;
    __shared__ unsigned short As[2 * BUFA];
    __shared__ unsigned short Bs[2 * BUFB];

    const int tid  = threadIdx.x;
    const int lane = tid & 63;
    const int w    = tid >> 6;
    const int mw   = w >> 2;
    const int nw   = w & 3;
    const int wr   = mw * 32;
    const int wc   = nw * 128;
    const int m0   = blockIdx.x * 64;

    f32x4 acc[2][8];
#pragma unroll
    for (int i = 0; i < 2; ++i)
#pragma unroll
        for (int j = 0; j < 8; ++j)
#pragma unroll
            for (int r = 0; r < 4; ++r) acc[i][j][r] = 0.f;

    auto stage = [&](int k0, int ph) {
#pragma unroll
        for (int ii = 0; ii < 5; ++ii) {
            const int g = ii * 8 + w;
            if (g >= 36) break;
            if (g < 4) {
                const unsigned short* gp = A +
                    (size_t)(m0 + g * 16 + (lane >> 2)) * 512 + k0 + (lane & 3) * 8;
                __builtin_amdgcn_global_load_lds(
                    (const __attribute__((address_space(1))) unsigned int*)gp,
                    (__attribute__((address_space(3))) unsigned int*)&As[ph * BUFA + g * 512],
                    16, 0, 0);
            } else {
                const int gb = g - 4;
                const unsigned short* gp = Bw +
                    (size_t)(gb * 16 + (lane >> 2)) * 512 + k0 + (lane & 3) * 8;
                __builtin_amdgcn_global_load_lds(
                    (const __attribute__((address_space(1))) unsigned int*)gp,
                    (__attribute__((address_space(3))) unsigned int*)&Bs[ph * BUFB + gb * 512],
                    16, 0, 0);
            }
        }
    };

    stage(0, 0);
    __syncthreads();

    int cur = 0;
    for (int t = 0; t < 16; ++t) {
        if (t + 1 < 16) stage((t + 1) << 5, cur ^ 1);
        bf16x8 af[2], bfr[8];
#pragma unroll
        for (int i = 0; i < 2; ++i)
            af[i] = *(const bf16x8*)&As[cur * BUFA + (wr + i * 16 + (lane & 15)) * 32 + (lane >> 4) * 8];
#pragma unroll
        for (int j = 0; j < 8; ++j)
            bfr[j] = *(const bf16x8*)&Bs[cur * BUFB + (wc + j * 16 + (lane & 15)) * 32 + (lane >> 4) * 8];
#pragma unroll
        for (int i = 0; i < 2; ++i)
#pragma unroll
            for (int j = 0; j < 8; ++j)
                acc[i][j] = __builtin_amdgcn_mfma_f32_16x16x32_bf16(af[i], bfr[j], acc[i][j], 0, 0, 0);
        __syncthreads();
        cur ^= 1;
    }

    float* SS = (float*)As;
    float* SQ = SS + 256;

#pragma unroll
    for (int i = 0; i < 2; ++i) {
#pragma unroll
        for (int r = 0; r < 4; ++r) {
            float p = 0.f, q2 = 0.f;
#pragma unroll
            for (int j = 0; j < 8; ++j) {
                float x = acc[i][j][r];
                p += x; q2 += x * x;
            }
#pragma unroll
            for (int off = 8; off >= 1; off >>= 1) {
                p  += __shfl_xor(p, off);
                q2 += __shfl_xor(q2, off);
            }
            if ((lane & 15) == 0) {
                const int row = wr + i * 16 + (lane >> 4) * 4 + r;
                SS[row * 4 + nw] = p;
                SQ[row * 4 + nw] = q2;
            }
        }
    }
    __syncthreads();

    float murow[2][4], invrow[2][4];
#pragma unroll
    for (int i = 0; i < 2; ++i) {
#pragma unroll
        for (int r = 0; r < 4; ++r) {
            const int row = wr + i * 16 + (lane >> 4) * 4 + r;
            const float s  = SS[row * 4] + SS[row * 4 + 1] + SS[row * 4 + 2] + SS[row * 4 + 3];
            const float sq = SQ[row * 4] + SQ[row * 4 + 1] + SQ[row * 4 + 2] + SQ[row * 4 + 3];
            const float mu  = s * (1.f / D_SZ);
            const float var = sq * (1.f / D_SZ) - mu * mu;
            murow[i][r]  = mu;
            invrow[i][r] = rsqrtf(var + 1e-6f);
        }
    }

    float lw[8], lb[8];
#pragma unroll
    for (int j = 0; j < 8; ++j) {
        const int col = wc + j * 16 + (lane & 15);
        lw[j] = ln_w[col];
        lb[j] = ln_b[col];
    }

#pragma unroll
    for (int i = 0; i < 2; ++i) {
#pragma unroll
        for (int j = 0; j < 8; ++j) {
            const int col = wc + j * 16 + (lane & 15);
#pragma unroll
            for (int r = 0; r < 4; ++r) {
                const int row = m0 + wr + i * 16 + (lane >> 4) * 4 + r;
                const float y =
                    (acc[i][j][r] - murow[i][r]) * invrow[i][r] * lw[j] + lb[j];
                __builtin_nontemporal_store(y, &out[(size_t)row * D_SZ + col]);
            }
        }
    }
}

// ---------------------------------------------------------------------------
// prep: z<8 -> transpose+cast v batch z; z==8 -> weight cast + rowsum zero.
// grid (16, 64, 9), 256 thr.
// ---------------------------------------------------------------------------
__global__ __launch_bounds__(256) void prep(
    const float* __restrict__ v, unsigned short* __restrict__ vT,
    const float* __restrict__ a, const float* __restrict__ bb,
    const float* __restrict__ c,
    unsigned short* __restrict__ oa, unsigned short* __restrict__ ob,
    unsigned short* __restrict__ oc, float* __restrict__ rowsum)
{
    const int tid = threadIdx.x;
    if (blockIdx.z == 8) {
        const int id = blockIdx.y * 16 + blockIdx.x;   // 0..1023
        if (id < 384) {
            const float* src = id < 128 ? a : id < 256 ? bb : c;
            unsigned short* dst = id < 128 ? oa : id < 256 ? ob : oc;
            const int blk = id & 127;
            const int i = (blk * 256 + tid) * 8;
            float4 f0 = *(const float4*)(src + i);
            float4 f1 = *(const float4*)(src + i + 4);
            ushort8 p;
            p[0] = f2bf(f0.x); p[1] = f2bf(f0.y); p[2] = f2bf(f0.z); p[3] = f2bf(f0.w);
            p[4] = f2bf(f1.x); p[5] = f2bf(f1.y); p[6] = f2bf(f1.z); p[7] = f2bf(f1.w);
            *(ushort8*)(dst + i) = p;
        } else if (id < 448) {
            const int idx = (id - 384) * 256 + tid;
            if (idx < NB * S_SZ) rowsum[idx] = 0.f;
        }
        return;
    }

    __shared__ float tile[32][33];
    const int b  = blockIdx.z;
    const int d0 = blockIdx.x * 32;
    const int s0 = blockIdx.y * 32;
    const int tx = tid & 31;
    const int ty = tid >> 5;
    const float* vb = v + (size_t)b * S_SZ * D_SZ;
    unsigned short* vTb = vT + (size_t)b * D_SZ * S_SZ;

#pragma unroll
    for (int j = 0; j < 32; j += 8)
        tile[ty + j][tx] = vb[(size_t)(s0 + ty + j) * D_SZ + d0 + tx];
    __syncthreads();
#pragma unroll
    for (int j = 0; j < 32; j += 8)
        vTb[(size_t)(d0 + ty + j) * S_SZ + s0 + tx] = f2bf(tile[tx][ty + j]);
}

// ---------------------------------------------------------------------------
extern "C" void kernel_launch(void* const* d_in, const int* in_sizes, int n_in,
                              void* d_out, int out_size, void* d_ws, size_t ws_size,
                              hipStream_t stream)
{
    const float* q    = (const float*)d_in[0];
    const float* k    = (const float*)d_in[1];
    const float* v    = (const float*)d_in[2];
    const float* w_qs = (const float*)d_in[3];
    const float* w_ks = (const float*)d_in[4];
    const float* w_fc = (const float*)d_in[5];
    const float* ln_w = (const float*)d_in[6];
    const float* ln_b = (const float*)d_in[7];

    float* out  = (float*)d_out;
    float* attn = out + (size_t)NB * S_SZ * D_SZ;

    const size_t MD = (size_t)NB * S_SZ * D_SZ;
    const size_t WW = (size_t)D_SZ * D_SZ;
    unsigned short* qp   = (unsigned short*)d_ws;
    unsigned short* kp   = qp + MD;
    unsigned short* vT   = kp + MD;
    unsigned short* sc   = vT + MD;
    unsigned short* wqb  = sc + (size_t)NB * S_SZ * S_SZ;
    unsigned short* wkb  = wqb + WW;
    unsigned short* wfb  = wkb + WW;
    float*          rsum = (float*)(wfb + WW);
    unsigned short* out1 = qp;

    const float inv_scale = 0.04419417382415922f;

    // prep: v transpose+cast (z<8), weight cast + rowsum zero (z=8)
    prep<<<dim3(16, 64, 9), dim3(256), 0, stream>>>(
        v, vT, w_qs, w_ks, w_fc, wqb, wkb, wfb, rsum);
    // qp = q @ w_qs^T, kp = k @ w_ks^T (scores8 engine, reg-staged fp32 A)
    proj256<<<dim3(64, 2, 2), dim3(512), 0, stream>>>(q, k, wqb, wkb, qp, kp);
    // e = exp(qp @ kp^T / sqrt(512)) -> bf16 + atomic rowsum
    scores8<<<dim3(512), dim3(512), 0, stream>>>(qp, kp, sc, rsum, inv_scale);
    // out1 = (e @ v)/rowsum + v; attn fp32 (nt) from staged e-tiles
    pv8<<<dim3(256), dim3(512), 0, stream>>>(sc, vT, v, out1, rsum, attn);
    // out = LN(out1 @ w_fc^T) fused, nt stores
    fc_ln<<<dim3(256), dim3(512), 0, stream>>>(out1, wfb, out, ln_w, ln_b);
}

// Round 16
// 183.463 us; speedup vs baseline: 1.0085x; 1.0085x over previous
//
#include <hip/hip_runtime.h>

typedef short bf16x8 __attribute__((ext_vector_type(8)));
typedef float f32x4 __attribute__((ext_vector_type(4)));
typedef unsigned short ushort8 __attribute__((ext_vector_type(8)));

#define S_SZ 2048
#define D_SZ 512
#define NB 8

__device__ __forceinline__ unsigned short f2bf(float f) {
    unsigned int u = __float_as_uint(f);
    unsigned int r = (u + 0x7FFFu + ((u >> 16) & 1u)) >> 16;
    return (unsigned short)r;
}
__device__ __forceinline__ float bf2f(unsigned short u) {
    return __uint_as_float((unsigned int)u << 16);
}

// ---------------------------------------------------------------------------
// scores8: e = exp((qp @ kp^T) * inv_scale) -> bf16 sc, + atomic rowsum.
// 256x256 tile, BK=64, 512 thr = 8 waves (2M x 4N). T2 XOR-swizzled LDS.
// ---------------------------------------------------------------------------
__global__ __launch_bounds__(512, 2) void scores8(
    const unsigned short* __restrict__ qp, const unsigned short* __restrict__ kp,
    unsigned short* __restrict__ sc, float* __restrict__ rowsum, float inv_scale)
{
    __shared__ unsigned short Abuf[2 * 256 * 64];
    __shared__ unsigned short Bbuf[2 * 256 * 64];
    constexpr int TB = 256 * 64;

    const int tid  = threadIdx.x;
    const int lane = tid & 63;
    const int w    = tid >> 6;
    const int wm   = w >> 2;
    const int wn   = w & 3;

    const int lin = blockIdx.x;
    const int b   = lin & 7;
    const int tt  = lin >> 3;
    const int m0  = (tt & 7) * 256;
    const int n0  = (tt >> 3) * 256;

    const unsigned short* Ag = qp + (size_t)b * (S_SZ * D_SZ);
    const unsigned short* Bg = kp + (size_t)b * (S_SZ * D_SZ);

    auto stage_half = [&](int opnd, int kt, int h) {
        const int k0 = kt * 64;
        const unsigned short* src = opnd ? Bg : Ag;
        unsigned short* dstb = opnd ? Bbuf : Abuf;
        const int base0 = opnd ? n0 : m0;
        const int swzc = ((lane & 7) ^ ((lane >> 3) & 7)) * 8;
#pragma unroll
        for (int j = 0; j < 2; ++j) {
            const int chunk = w * 2 + j;
            const unsigned short* g = src +
                (size_t)(base0 + h * 128 + chunk * 8 + (lane >> 3)) * 512 +
                k0 + swzc;
            __builtin_amdgcn_global_load_lds(
                (const __attribute__((address_space(1))) unsigned int*)g,
                (__attribute__((address_space(3))) unsigned int*)
                    &dstb[(kt & 1) * TB + h * (128 * 64) + chunk * 512],
                16, 0, 0);
        }
    };

    f32x4 acc[8][4];
#pragma unroll
    for (int i = 0; i < 8; ++i)
#pragma unroll
        for (int j = 0; j < 4; ++j)
#pragma unroll
            for (int r = 0; r < 4; ++r) acc[i][j][r] = 0.f;

    stage_half(0, 0, 0); stage_half(0, 0, 1);
    stage_half(1, 0, 0); stage_half(1, 0, 1);
    asm volatile("s_waitcnt vmcnt(0)" ::: "memory");
    __builtin_amdgcn_s_barrier();
    __builtin_amdgcn_sched_barrier(0);

    int cur = 0;
    for (int kt = 0; kt < 8; ++kt) {
        bf16x8 bf[4][2];
#pragma unroll
        for (int j = 0; j < 4; ++j)
#pragma unroll
            for (int s = 0; s < 2; ++s) {
                const int row = wn * 64 + j * 16 + (lane & 15);
                const int g   = (s * 4 + (lane >> 4)) ^ (lane & 7);
                bf[j][s] = *(const bf16x8*)&Bbuf[cur * TB + row * 64 + g * 8];
            }

#pragma unroll
        for (int q = 0; q < 4; ++q) {
            bf16x8 af[2][2];
#pragma unroll
            for (int i = 0; i < 2; ++i)
#pragma unroll
                for (int s = 0; s < 2; ++s) {
                    const int row = wm * 128 + (2 * q + i) * 16 + (lane & 15);
                    const int g   = (s * 4 + (lane >> 4)) ^ (lane & 7);
                    af[i][s] = *(const bf16x8*)&Abuf[cur * TB + row * 64 + g * 8];
                }
            if (kt + 1 < 8) {
                if      (q == 0) stage_half(0, kt + 1, 0);
                else if (q == 1) stage_half(0, kt + 1, 1);
                else if (q == 2) stage_half(1, kt + 1, 0);
                else             stage_half(1, kt + 1, 1);
            }
            __builtin_amdgcn_s_setprio(1);
#pragma unroll
            for (int i = 0; i < 2; ++i)
#pragma unroll
                for (int j = 0; j < 4; ++j)
#pragma unroll
                    for (int s = 0; s < 2; ++s)
                        acc[2 * q + i][j] = __builtin_amdgcn_mfma_f32_16x16x32_bf16(
                            af[i][s], bf[j][s], acc[2 * q + i][j], 0, 0, 0);
            __builtin_amdgcn_s_setprio(0);
        }

        asm volatile("" ::: "memory");
        __builtin_amdgcn_s_barrier();
        asm volatile("s_waitcnt vmcnt(0)" ::: "memory");
        __builtin_amdgcn_s_barrier();
        __builtin_amdgcn_sched_barrier(0);
        cur ^= 1;
    }

    const int rowb = m0 + wm * 128 + (lane >> 4) * 4;
    const int colb = n0 + wn * 64 + (lane & 15);
#pragma unroll
    for (int i = 0; i < 8; ++i) {
#pragma unroll
        for (int r = 0; r < 4; ++r) {
            const int row = rowb + i * 16 + r;
            float p = 0.f;
#pragma unroll
            for (int j = 0; j < 4; ++j) {
                const int col = colb + j * 16;
                float e = __expf(acc[i][j][r] * inv_scale);
                unsigned short eb = f2bf(e);
                sc[(size_t)b * ((long long)S_SZ * S_SZ) + (size_t)row * S_SZ + col] = eb;
                p += bf2f(eb);
            }
#pragma unroll
            for (int off = 8; off >= 1; off >>= 1) p += __shfl_xor(p, off);
            if ((lane & 15) == 0)
                atomicAdd(&rowsum[b * 2048 + row], p);
        }
    }
}

// ---------------------------------------------------------------------------
// pv8: out1 = (e @ v)/rowsum + v (bf16) AND attn fp32 = e/rowsum (non-temporal
// stores -- attn is never re-read; keeps sc/vT hot in the XCD L2).
// 256x128 tile, BK=64, 512 thr = 8 waves. T2 swizzle. Counted vmcnt(8) on
// owned tiles (attn stores stay in flight across the boundary).
// ---------------------------------------------------------------------------
__global__ __launch_bounds__(512, 1) void pv8(
    const unsigned short* __restrict__ sc, const unsigned short* __restrict__ vT,
    const float* __restrict__ v, unsigned short* __restrict__ out1,
    const float* __restrict__ rowsum, float* __restrict__ attnW)
{
    __shared__ unsigned short Abuf[2 * 256 * 64];
    __shared__ unsigned short Bbuf[2 * 128 * 64];
    constexpr int TA = 256 * 64;
    constexpr int TBb = 128 * 64;

    const int tid  = threadIdx.x;
    const int lane = tid & 63;
    const int w    = tid >> 6;
    const int wm   = w >> 2;
    const int wn   = w & 3;

    const int lin = blockIdx.x;
    const int b   = lin & 7;
    const int t   = lin >> 3;
    const int m0  = (t & 7) * 256;
    const int nq  = t >> 3;
    const int n0  = nq * 128;

    const unsigned short* Ag = sc + (size_t)b * ((long long)S_SZ * S_SZ);
    const unsigned short* Bg = vT + (size_t)b * (D_SZ * S_SZ);
    const int swzg = (lane & 7) ^ ((lane >> 3) & 7);

    auto stageA = [&](int kt, int h) {
#pragma unroll
        for (int j = 0; j < 2; ++j) {
            const int chunk = w * 2 + j;
            const unsigned short* g = Ag +
                (size_t)(m0 + h * 128 + chunk * 8 + (lane >> 3)) * S_SZ +
                kt * 64 + swzg * 8;
            __builtin_amdgcn_global_load_lds(
                (const __attribute__((address_space(1))) unsigned int*)g,
                (__attribute__((address_space(3))) unsigned int*)
                    &Abuf[(kt & 1) * TA + h * (128 * 64) + chunk * 512],
                16, 0, 0);
        }
    };
    auto stageB = [&](int kt) {
#pragma unroll
        for (int j = 0; j < 2; ++j) {
            const int chunk = w * 2 + j;
            const unsigned short* g = Bg +
                (size_t)(n0 + chunk * 8 + (lane >> 3)) * S_SZ +
                kt * 64 + swzg * 8;
            __builtin_amdgcn_global_load_lds(
                (const __attribute__((address_space(1))) unsigned int*)g,
                (__attribute__((address_space(3))) unsigned int*)
                    &Bbuf[(kt & 1) * TBb + chunk * 512],
                16, 0, 0);
        }
    };

    float sinv[2][2];
#pragma unroll
    for (int h = 0; h < 2; ++h)
#pragma unroll
        for (int j = 0; j < 2; ++j)
            sinv[h][j] = 1.f / rowsum[b * 2048 + m0 + h * 128 + (w * 2 + j) * 8 + (lane >> 3)];

    auto store_attn = [&](int kt, int cu) {
#pragma unroll
        for (int h = 0; h < 2; ++h)
#pragma unroll
            for (int j = 0; j < 2; ++j) {
                const int chunk = w * 2 + j;
                ushort8 ev = *(const ushort8*)&Abuf[cu * TA + h * (128 * 64) +
                                                    chunk * 512 + lane * 8];
                const float is = sinv[h][j];
                f32x4 o0, o1;
                o0[0] = bf2f(ev[0]) * is; o0[1] = bf2f(ev[1]) * is;
                o0[2] = bf2f(ev[2]) * is; o0[3] = bf2f(ev[3]) * is;
                o1[0] = bf2f(ev[4]) * is; o1[1] = bf2f(ev[5]) * is;
                o1[2] = bf2f(ev[6]) * is; o1[3] = bf2f(ev[7]) * is;
                float* dst = attnW + (size_t)b * ((long long)S_SZ * S_SZ) +
                             (size_t)(m0 + h * 128 + chunk * 8 + (lane >> 3)) * S_SZ +
                             kt * 64 + swzg * 8;
                __builtin_nontemporal_store(o0, (f32x4*)dst);
                __builtin_nontemporal_store(o1, (f32x4*)(dst + 4));
            }
    };

    f32x4 acc[8][2];
#pragma unroll
    for (int i = 0; i < 8; ++i)
#pragma unroll
        for (int j = 0; j < 2; ++j)
#pragma unroll
            for (int r = 0; r < 4; ++r) acc[i][j][r] = 0.f;

    stageA(0, 0); stageA(0, 1); stageB(0);
    asm volatile("s_waitcnt vmcnt(0)" ::: "memory");
    __builtin_amdgcn_s_barrier();
    __builtin_amdgcn_sched_barrier(0);

    int cur = 0;
    for (int kt = 0; kt < 32; ++kt) {
        const bool owned = (kt >> 3) == nq;
        bf16x8 bfr[2][2];
#pragma unroll
        for (int j = 0; j < 2; ++j)
#pragma unroll
            for (int s = 0; s < 2; ++s) {
                const int row = wn * 32 + j * 16 + (lane & 15);
                const int g   = (s * 4 + (lane >> 4)) ^ (lane & 7);
                bfr[j][s] = *(const bf16x8*)&Bbuf[cur * TBb + row * 64 + g * 8];
            }

#pragma unroll
        for (int q = 0; q < 4; ++q) {
            bf16x8 af[2][2];
#pragma unroll
            for (int i = 0; i < 2; ++i)
#pragma unroll
                for (int s = 0; s < 2; ++s) {
                    const int row = wm * 128 + (2 * q + i) * 16 + (lane & 15);
                    const int g   = (s * 4 + (lane >> 4)) ^ (lane & 7);
                    af[i][s] = *(const bf16x8*)&Abuf[cur * TA + row * 64 + g * 8];
                }
            if (kt + 1 < 32) {
                if      (q == 0) stageA(kt + 1, 0);
                else if (q == 1) stageA(kt + 1, 1);
                else if (q == 2) stageB(kt + 1);
            }
            if (q == 3 && owned) store_attn(kt, cur);
            __builtin_amdgcn_s_setprio(1);
#pragma unroll
            for (int i = 0; i < 2; ++i)
#pragma unroll
                for (int j = 0; j < 2; ++j)
#pragma unroll
                    for (int s = 0; s < 2; ++s)
                        acc[2 * q + i][j] = __builtin_amdgcn_mfma_f32_16x16x32_bf16(
                            af[i][s], bfr[j][s], acc[2 * q + i][j], 0, 0, 0);
            __builtin_amdgcn_s_setprio(0);
        }

        asm volatile("" ::: "memory");
        __builtin_amdgcn_s_barrier();
        if (kt + 1 < 32) {
            if (owned) asm volatile("s_waitcnt vmcnt(8)" ::: "memory");
            else       asm volatile("s_waitcnt vmcnt(0)" ::: "memory");
        }
        __builtin_amdgcn_s_barrier();
        __builtin_amdgcn_sched_barrier(0);
        cur ^= 1;
    }

    const int rowb = m0 + wm * 128 + (lane >> 4) * 4;
    const int colb = n0 + wn * 32 + (lane & 15);
#pragma unroll
    for (int i = 0; i < 8; ++i) {
#pragma unroll
        for (int r = 0; r < 4; ++r) {
            const int row = rowb + i * 16 + r;
            const float inv = 1.f / rowsum[b * 2048 + row];
#pragma unroll
            for (int j = 0; j < 2; ++j) {
                const int col = colb + j * 16;
                float vv = acc[i][j][r] * inv +
                           v[(size_t)b * (S_SZ * D_SZ) + (size_t)row * D_SZ + col];
                out1[(size_t)b * (S_SZ * D_SZ) + (size_t)row * D_SZ + col] = f2bf(vv);
            }
        }
    }
}

// ---------------------------------------------------------------------------
// proj256: qp = q @ w_qs^T, kp = k @ w_ks^T on the scores8 engine.
// 256x256 tile, BK=64, 512 thr = 8 waves (2M x 4N), per-wave C = 128x64.
// B (bf16 weights) via global_load_lds + T2 pre-swizzled source; A (fp32)
// reg-staged: issue 8 f32x4 loads at q0, f2bf + swizzled ds_write_b128 at
// q3 (T14 issue-early/write-late; compiler inserts the vm waits for ald).
// Grid (64, 2, 2): x = m-tiles (16384 rows), y = n-tiles, z = op (q/k).
// ---------------------------------------------------------------------------
__global__ __launch_bounds__(512, 1) void proj256(
    const float* __restrict__ q, const float* __restrict__ k,
    const unsigned short* __restrict__ wq, const unsigned short* __restrict__ wk,
    unsigned short* __restrict__ qp, unsigned short* __restrict__ kp)
{
    __shared__ unsigned short Abuf[2 * 256 * 64];
    __shared__ unsigned short Bbuf[2 * 256 * 64];
    constexpr int TB = 256 * 64;

    const int tid  = threadIdx.x;
    const int lane = tid & 63;
    const int w    = tid >> 6;
    const int wm   = w >> 2;
    const int wn   = w & 3;
    const int m0   = blockIdx.x * 256;
    const int n0   = blockIdx.y * 256;

    const float* Ap = blockIdx.z ? k : q;
    const unsigned short* Bp = blockIdx.z ? wk : wq;
    unsigned short* Cp = blockIdx.z ? kp : qp;

    // B staging: identical to scores8 (global_load_lds, pre-swizzled source)
    auto stageB = [&](int kt, int h) {
        const int swzc = ((lane & 7) ^ ((lane >> 3) & 7)) * 8;
#pragma unroll
        for (int j = 0; j < 2; ++j) {
            const int chunk = w * 2 + j;
            const unsigned short* g = Bp +
                (size_t)(n0 + h * 128 + chunk * 8 + (lane >> 3)) * 512 +
                kt * 64 + swzc;
            __builtin_amdgcn_global_load_lds(
                (const __attribute__((address_space(1))) unsigned int*)g,
                (__attribute__((address_space(3))) unsigned int*)
                    &Bbuf[(kt & 1) * TB + h * (128 * 64) + chunk * 512],
                16, 0, 0);
        }
    };

    // A staging (fp32 -> bf16): thread t owns row t>>1, granules (t&1)*4+0..3
    f32x4 ald[8];
    const int ar  = tid >> 1;            // 0..255
    const int ag0 = (tid & 1) * 4;       // first granule
    auto issueA = [&](int kt) {
        const float* gp = Ap + (size_t)(m0 + ar) * 512 + kt * 64 + ag0 * 8;
#pragma unroll
        for (int u = 0; u < 8; ++u)
            ald[u] = *(const f32x4*)(gp + u * 4);
    };
    auto writeA = [&](int kt) {
#pragma unroll
        for (int gg = 0; gg < 4; ++gg) {
            ushort8 p;
#pragma unroll
            for (int u = 0; u < 4; ++u) {
                p[u]     = f2bf(ald[gg * 2][u]);
                p[4 + u] = f2bf(ald[gg * 2 + 1][u]);
            }
            const int gl = ag0 + gg;
            *(ushort8*)&Abuf[(kt & 1) * TB + ar * 64 + (gl ^ (ar & 7)) * 8] = p;
        }
    };

    f32x4 acc[8][4];
#pragma unroll
    for (int i = 0; i < 8; ++i)
#pragma unroll
        for (int j = 0; j < 4; ++j)
#pragma unroll
            for (int r = 0; r < 4; ++r) acc[i][j][r] = 0.f;

    // prologue: stage K-tile 0 (A reg->LDS, B async), drain, sync
    issueA(0);
    stageB(0, 0); stageB(0, 1);
    writeA(0);
    asm volatile("s_waitcnt vmcnt(0) lgkmcnt(0)" ::: "memory");
    __builtin_amdgcn_s_barrier();
    __builtin_amdgcn_sched_barrier(0);

    int cur = 0;
    for (int kt = 0; kt < 8; ++kt) {
        bf16x8 bf[4][2];
#pragma unroll
        for (int j = 0; j < 4; ++j)
#pragma unroll
            for (int s = 0; s < 2; ++s) {
                const int row = wn * 64 + j * 16 + (lane & 15);
                const int g   = (s * 4 + (lane >> 4)) ^ (lane & 7);
                bf[j][s] = *(const bf16x8*)&Bbuf[cur * TB + row * 64 + g * 8];
            }

#pragma unroll
        for (int qd = 0; qd < 4; ++qd) {
            bf16x8 af[2][2];
#pragma unroll
            for (int i = 0; i < 2; ++i)
#pragma unroll
                for (int s = 0; s < 2; ++s) {
                    const int row = wm * 128 + (2 * qd + i) * 16 + (lane & 15);
                    const int g   = (s * 4 + (lane >> 4)) ^ (lane & 7);
                    af[i][s] = *(const bf16x8*)&Abuf[cur * TB + row * 64 + g * 8];
                }
            if (kt + 1 < 8) {
                if      (qd == 0) issueA(kt + 1);
                else if (qd == 1) stageB(kt + 1, 0);
                else if (qd == 2) stageB(kt + 1, 1);
                else              writeA(kt + 1);
            }
            __builtin_amdgcn_s_setprio(1);
#pragma unroll
            for (int i = 0; i < 2; ++i)
#pragma unroll
                for (int j = 0; j < 4; ++j)
#pragma unroll
                    for (int s = 0; s < 2; ++s)
                        acc[2 * qd + i][j] = __builtin_amdgcn_mfma_f32_16x16x32_bf16(
                            af[i][s], bf[j][s], acc[2 * qd + i][j], 0, 0, 0);
            __builtin_amdgcn_s_setprio(0);
        }

        asm volatile("" ::: "memory");
        __builtin_amdgcn_s_barrier();
        asm volatile("s_waitcnt vmcnt(0) lgkmcnt(0)" ::: "memory");
        __builtin_amdgcn_s_barrier();
        __builtin_amdgcn_sched_barrier(0);
        cur ^= 1;
    }

    const int rowb = m0 + wm * 128 + (lane >> 4) * 4;
    const int colb = n0 + wn * 64 + (lane & 15);
#pragma unroll
    for (int i = 0; i < 8; ++i)
#pragma unroll
        for (int j = 0; j < 4; ++j) {
            const int col = colb + j * 16;
#pragma unroll
            for (int r = 0; r < 4; ++r) {
                const int row = rowb + i * 16 + r;
                Cp[(size_t)row * 512 + col] = f2bf(acc[i][j][r]);
            }
        }
}

// ---------------------------------------------------------------------------
// Fused fc GEMM + LayerNorm; out stores non-temporal (never re-read).
// ---------------------------------------------------------------------------
__global__ __launch_bounds__(512) void fc_ln(
    const unsigned short* __restrict__ A,
    const unsigned short* __restrict__ Bw,
    float* __restrict__ out,
    const float* __restrict__ ln_w, const float* __restrict__ ln_b)
{
    constexpr int BUFA = 64 * 32;
    constexpr int BUFB = 512 * 32;
    __shared__ unsigned short As[2 * BUFA];
    __shared__ unsigned short Bs[2 * BUFB];

    const int tid  = threadIdx.x;
    const int lane = tid & 63;
    const int w    = tid >> 6;
    const int mw   = w >> 2;
    const int nw   = w & 3;
    const int wr   = mw * 32;
    const int wc   = nw * 128;
    const int m0   = blockIdx.x * 64;

    f32x4 acc[2][8];
#pragma unroll
    for (int i = 0; i < 2; ++i)
#pragma unroll
        for (int j = 0; j < 8; ++j)
#pragma unroll
            for (int r = 0; r < 4; ++r) acc[i][j][r] = 0.f;

    auto stage = [&](int k0, int ph) {
#pragma unroll
        for (int ii = 0; ii < 5; ++ii) {
            const int g = ii * 8 + w;
            if (g >= 36) break;
            if (g < 4) {
                const unsigned short* gp = A +
                    (size_t)(m0 + g * 16 + (lane >> 2)) * 512 + k0 + (lane & 3) * 8;
                __builtin_amdgcn_global_load_lds(
                    (const __attribute__((address_space(1))) unsigned int*)gp,
                    (__attribute__((address_space(3))) unsigned int*)&As[ph * BUFA + g * 512],
                    16, 0, 0);
            } else {
                const int gb = g - 4;
                const unsigned short* gp = Bw +
                    (size_t)(gb * 16 + (lane >> 2)) * 512 + k0 + (lane & 3) * 8;
                __builtin_amdgcn_global_load_lds(
                    (const __attribute__((address_space(1))) unsigned int*)gp,
                    (__attribute__((address_space(3))) unsigned int*)&Bs[ph * BUFB + gb * 512],
                    16, 0, 0);
            }
        }
    };

    stage(0, 0);
    __syncthreads();

    int cur = 0;
    for (int t = 0; t < 16; ++t) {
        if (t + 1 < 16) stage((t + 1) << 5, cur ^ 1);
        bf16x8 af[2], bfr[8];
#pragma unroll
        for (int i = 0; i < 2; ++i)
            af[i] = *(const bf16x8*)&As[cur * BUFA + (wr + i * 16 + (lane & 15)) * 32 + (lane >> 4) * 8];
#pragma unroll
        for (int j = 0; j < 8; ++j)
            bfr[j] = *(const bf16x8*)&Bs[cur * BUFB + (wc + j * 16 + (lane & 15)) * 32 + (lane >> 4) * 8];
#pragma unroll
        for (int i = 0; i < 2; ++i)
#pragma unroll
            for (int j = 0; j < 8; ++j)
                acc[i][j] = __builtin_amdgcn_mfma_f32_16x16x32_bf16(af[i], bfr[j], acc[i][j], 0, 0, 0);
        __syncthreads();
        cur ^= 1;
    }

    float* SS = (float*)As;
    float* SQ = SS + 256;

#pragma unroll
    for (int i = 0; i < 2; ++i) {
#pragma unroll
        for (int r = 0; r < 4; ++r) {
            float p = 0.f, q2 = 0.f;
#pragma unroll
            for (int j = 0; j < 8; ++j) {
                float x = acc[i][j][r];
                p += x; q2 += x * x;
            }
#pragma unroll
            for (int off = 8; off >= 1; off >>= 1) {
                p  += __shfl_xor(p, off);
                q2 += __shfl_xor(q2, off);
            }
            if ((lane & 15) == 0) {
                const int row = wr + i * 16 + (lane >> 4) * 4 + r;
                SS[row * 4 + nw] = p;
                SQ[row * 4 + nw] = q2;
            }
        }
    }
    __syncthreads();

    float murow[2][4], invrow[2][4];
#pragma unroll
    for (int i = 0; i < 2; ++i) {
#pragma unroll
        for (int r = 0; r < 4; ++r) {
            const int row = wr + i * 16 + (lane >> 4) * 4 + r;
            const float s  = SS[row * 4] + SS[row * 4 + 1] + SS[row * 4 + 2] + SS[row * 4 + 3];
            const float sq = SQ[row * 4] + SQ[row * 4 + 1] + SQ[row * 4 + 2] + SQ[row * 4 + 3];
            const float mu  = s * (1.f / D_SZ);
            const float var = sq * (1.f / D_SZ) - mu * mu;
            murow[i][r]  = mu;
            invrow[i][r] = rsqrtf(var + 1e-6f);
        }
    }

    float lw[8], lb[8];
#pragma unroll
    for (int j = 0; j < 8; ++j) {
        const int col = wc + j * 16 + (lane & 15);
        lw[j] = ln_w[col];
        lb[j] = ln_b[col];
    }

#pragma unroll
    for (int i = 0; i < 2; ++i) {
#pragma unroll
        for (int j = 0; j < 8; ++j) {
            const int col = wc + j * 16 + (lane & 15);
#pragma unroll
            for (int r = 0; r < 4; ++r) {
                const int row = m0 + wr + i * 16 + (lane >> 4) * 4 + r;
                const float y =
                    (acc[i][j][r] - murow[i][r]) * invrow[i][r] * lw[j] + lb[j];
                __builtin_nontemporal_store(y, &out[(size_t)row * D_SZ + col]);
            }
        }
    }
}

// ---------------------------------------------------------------------------
// prep: z<8 -> transpose+cast v batch z; z==8 -> weight cast + rowsum zero.
// grid (16, 64, 9), 256 thr.
// ---------------------------------------------------------------------------
__global__ __launch_bounds__(256) void prep(
    const float* __restrict__ v, unsigned short* __restrict__ vT,
    const float* __restrict__ a, const float* __restrict__ bb,
    const float* __restrict__ c,
    unsigned short* __restrict__ oa, unsigned short* __restrict__ ob,
    unsigned short* __restrict__ oc, float* __restrict__ rowsum)
{
    const int tid = threadIdx.x;
    if (blockIdx.z == 8) {
        const int id = blockIdx.y * 16 + blockIdx.x;   // 0..1023
        if (id < 384) {
            const float* src = id < 128 ? a : id < 256 ? bb : c;
            unsigned short* dst = id < 128 ? oa : id < 256 ? ob : oc;
            const int blk = id & 127;
            const int i = (blk * 256 + tid) * 8;
            float4 f0 = *(const float4*)(src + i);
            float4 f1 = *(const float4*)(src + i + 4);
            ushort8 p;
            p[0] = f2bf(f0.x); p[1] = f2bf(f0.y); p[2] = f2bf(f0.z); p[3] = f2bf(f0.w);
            p[4] = f2bf(f1.x); p[5] = f2bf(f1.y); p[6] = f2bf(f1.z); p[7] = f2bf(f1.w);
            *(ushort8*)(dst + i) = p;
        } else if (id < 448) {
            const int idx = (id - 384) * 256 + tid;
            if (idx < NB * S_SZ) rowsum[idx] = 0.f;
        }
        return;
    }

    __shared__ float tile[32][33];
    const int b  = blockIdx.z;
    const int d0 = blockIdx.x * 32;
    const int s0 = blockIdx.y * 32;
    const int tx = tid & 31;
    const int ty = tid >> 5;
    const float* vb = v + (size_t)b * S_SZ * D_SZ;
    unsigned short* vTb = vT + (size_t)b * D_SZ * S_SZ;

#pragma unroll
    for (int j = 0; j < 32; j += 8)
        tile[ty + j][tx] = vb[(size_t)(s0 + ty + j) * D_SZ + d0 + tx];
    __syncthreads();
#pragma unroll
    for (int j = 0; j < 32; j += 8)
        vTb[(size_t)(d0 + ty + j) * S_SZ + s0 + tx] = f2bf(tile[tx][ty + j]);
}

// ---------------------------------------------------------------------------
extern "C" void kernel_launch(void* const* d_in, const int* in_sizes, int n_in,
                              void* d_out, int out_size, void* d_ws, size_t ws_size,
                              hipStream_t stream)
{
    const float* q    = (const float*)d_in[0];
    const float* k    = (const float*)d_in[1];
    const float* v    = (const float*)d_in[2];
    const float* w_qs = (const float*)d_in[3];
    const float* w_ks = (const float*)d_in[4];
    const float* w_fc = (const float*)d_in[5];
    const float* ln_w = (const float*)d_in[6];
    const float* ln_b = (const float*)d_in[7];

    float* out  = (float*)d_out;
    float* attn = out + (size_t)NB * S_SZ * D_SZ;

    const size_t MD = (size_t)NB * S_SZ * D_SZ;
    const size_t WW = (size_t)D_SZ * D_SZ;
    unsigned short* qp   = (unsigned short*)d_ws;
    unsigned short* kp   = qp + MD;
    unsigned short* vT   = kp + MD;
    unsigned short* sc   = vT + MD;
    unsigned short* wqb  = sc + (size_t)NB * S_SZ * S_SZ;
    unsigned short* wkb  = wqb + WW;
    unsigned short* wfb  = wkb + WW;
    float*          rsum = (float*)(wfb + WW);
    unsigned short* out1 = qp;

    const float inv_scale = 0.04419417382415922f;

    // prep: v transpose+cast (z<8), weight cast + rowsum zero (z=8)
    prep<<<dim3(16, 64, 9), dim3(256), 0, stream>>>(
        v, vT, w_qs, w_ks, w_fc, wqb, wkb, wfb, rsum);
    // qp = q @ w_qs^T, kp = k @ w_ks^T (scores8 engine, reg-staged fp32 A)
    proj256<<<dim3(64, 2, 2), dim3(512), 0, stream>>>(q, k, wqb, wkb, qp, kp);
    // e = exp(qp @ kp^T / sqrt(512)) -> bf16 + atomic rowsum
    scores8<<<dim3(512), dim3(512), 0, stream>>>(qp, kp, sc, rsum, inv_scale);
    // out1 = (e @ v)/rowsum + v; attn fp32 (nt) from staged e-tiles
    pv8<<<dim3(256), dim3(512), 0, stream>>>(sc, vT, v, out1, rsum, attn);
    // out = LN(out1 @ w_fc^T) fused, nt stores
    fc_ln<<<dim3(256), dim3(512), 0, stream>>>(out1, wfb, out, ln_w, ln_b);
}